// Round 7
// baseline (284.073 us; speedup 1.0000x reference)
//
#include <hip/hip_runtime.h>
#include <stdint.h>

// B=128, S=1024, LAST=258, FEAT=255, HIDDEN=1024 — all f32 in/out.
#define NBATCH 128
#define SEQ    1024
#define ROWE   258
#define NPART  8

// ws layout (bytes), total ~3.41 MB (part region shrank with NPART=8; offsets kept)
#define WS_KQP   0                       // float kqp[4][128][256]     512 KB
#define WS_PART  524288                  // float part[128][8][260]   1.06 MB
#define WS_WF    2654208                 // float wf[128][256]         128 KB
#define WS_REST  2785280                 // float resT[1024][128]      512 KB
#define WS_H1P   3309568                 // float h1pre[128][512]      256 KB

// NOTE (R1): cross-block fusion via __threadfence = L2 wb/inv on gfx950 -> 235 µs attn. Never.
// NOTE (R2/R4): __launch_bounds__(256,W) caps VGPR at ~256/W (W=8->32, W=4->64).
//   Spill signature: small VGPR_Count + WRITE_SIZE >> legit output.
// NOTE (R5): 2-pair interleave + 2-deep prefetch NEUTRAL -> not shuffle/prefetch bound.
// NOTE (R6): 32-lane/row "wide load" NEUTRAL — lanes strided 32 B still touch every
//   line of TWO rows per instruction, half-used. Line-touches per byte unchanged.
//   This round: 64-lane/row, lane = one float4 at f=4*lane -> each wave instr
//   covers ONE contiguous 1-KB row, all bytes of every touched line consumed.

static __device__ __forceinline__ float fexp2(float x){ return __builtin_amdgcn_exp2f(x); }

typedef float floatx4 __attribute__((ext_vector_type(4)));
// 16-B load from an 8-B-aligned address: lowers to global_load_dwordx4 on gfx950
// (unaligned-access-mode: multi-dword global loads need only dword alignment).
static __device__ __forceinline__ floatx4 load16a8(const float* p) {
    floatx4 r;
    __builtin_memcpy(&r, __builtin_assume_aligned(p, 8), 16);
    return r;
}

// ---------------------------------------------------------------------------
// qk: grid (64 batch-pairs, 4 h-quarters). kqp[hh][b][f] = partial over h-quarter
//     of (qb[h] + sum_j archi[b][j] qW[h][j]) * kW[h][f]. Unscaled; attn sums the
//     4 partials and applies log2(e)/sqrt(258). Also zero-inits h1pre and d_out
//     (consumed via atomicAdd later). q.kb dropped: softmax-invariant shift.
__global__ __launch_bounds__(256) void qk_kernel(const float* __restrict__ in,
    const float* __restrict__ kW, const float* __restrict__ qW,
    const float* __restrict__ qb, float* __restrict__ kqp,
    float* __restrict__ h1pre, float* __restrict__ out)
{
    __shared__ float qv[2][256];
    const int bb = blockIdx.x;         // 0..63
    const int hh = blockIdx.y;         // 0..3
    const int t  = threadIdx.x;
    const int b0 = bb * 2;
    if (hh == 0) {
        h1pre[(size_t)b0 * 512 + t]             = 0.f;
        h1pre[(size_t)b0 * 512 + 256 + t]       = 0.f;
        h1pre[(size_t)(b0 + 1) * 512 + t]       = 0.f;
        h1pre[(size_t)(b0 + 1) * 512 + 256 + t] = 0.f;
        if (t < 4) out[b0 * 2 + t] = 0.f;
    }
    const int h = hh * 256 + t;
    const float w0 = qW[h * 3 + 0], w1 = qW[h * 3 + 1], w2 = qW[h * 3 + 2], bq = qb[h];
    #pragma unroll
    for (int u = 0; u < 2; u++) {
        const size_t abase = (size_t)(b0 + u) * (SEQ * ROWE) + 255; // input[b,0,255..257]
        qv[u][t] = bq + in[abase] * w0 + in[abase + 1] * w1 + in[abase + 2] * w2;
    }
    __syncthreads();
    const int col = (t < 255) ? t : 254;            // t==255 is a pad slot
    const float* kWp = kW + (size_t)(hh * 256) * 255 + col;
    float acc0 = 0.f, acc1 = 0.f;
    #pragma unroll 16
    for (int i = 0; i < 256; i++) {
        const float kv = kWp[(size_t)i * 255];      // coalesced across t
        acc0 = fmaf(qv[0][i], kv, acc0);            // LDS broadcast reads
        acc1 = fmaf(qv[1][i], kv, acc1);
    }
    kqp[(size_t)((hh << 7) + b0) * 256 + t]       = (t < 255) ? acc0 : 0.f;
    kqp[(size_t)((hh << 7) + b0 + 1) * 256 + t]   = (t < 255) ? acc1 : 0.f;
}

// ---------------------------------------------------------------------------
// attn: grid (8,128) — (S-chunk of 128 rows, batch). 64 lanes per row; lane
// owns f = 4*lane..4*lane+3, loaded as ONE 16-B dwordx4 -> each wave load
// covers one contiguous 1-KB row (line-perfect streaming; R6 note). 6-step
// butterfly over the full wave; exp2-domain online softmax; 1-deep row
// prefetch. Lane 63's f=255 slot is killed by kqp's zero pad. 4 wave states
// merged through LDS. (256,6): VGPR cap ~42, live set ~30 -> 6 waves/SIMD.
__global__ __launch_bounds__(256, 6) void attn_kernel(const float* __restrict__ in,
                                                      const float* __restrict__ kqp,
                                                      float* __restrict__ part)
{
    __shared__ float sM[4], sL[4], sacc[4][256];
    const int p = blockIdx.x, b = blockIdx.y;
    const int t = threadIdx.x, w = t >> 6, lane = t & 63;

    const float SCALE = (float)(1.4426950408889634 / 16.062378404209142); // log2(e)/sqrt(258)
    // k: lane covers f = 4*lane..4*lane+3. kqp rows 1 KB-aligned -> float4 ok.
    float k[4];
    {
        float s0=0.f, s1=0.f, s2=0.f, s3=0.f;
        #pragma unroll
        for (int hh = 0; hh < 4; hh++) {
            const float4 u = *(const float4*)(kqp + (size_t)((hh << 7) + b) * 256 + lane * 4);
            s0 += u.x; s1 += u.y; s2 += u.z; s3 += u.w;
        }
        k[0] = s0 * SCALE; k[1] = s1 * SCALE; k[2] = s2 * SCALE; k[3] = s3 * SCALE;
    }

    // wave w covers rows r = p*128 + w*32 + i, i=0..31. Row byte base = r*1032
    // (8-aligned); per-lane 16 B at +lane*16 -> 8-B-aligned dwordx4 (load16a8).
    const float* rp = in + ((size_t)b * SEQ + p * 128 + w * 32) * ROWE + lane * 4;

    float x[4], xn[4], a[4] = {0.f, 0.f, 0.f, 0.f};
    {
        const floatx4 v = load16a8(rp);
        x[0] = v.x; x[1] = v.y; x[2] = v.z; x[3] = v.w;
    }
    rp += ROWE;
    float m = -INFINITY, l = 0.f;

    #pragma unroll 8
    for (int i = 0; i < 32; i++) {
        if (i < 31) {                      // prefetch next row
            const floatx4 v = load16a8(rp);
            xn[0] = v.x; xn[1] = v.y; xn[2] = v.z; xn[3] = v.w;
            rp += ROWE;
        }
        float d = fmaf(x[0], k[0], fmaf(x[1], k[1], fmaf(x[2], k[2], x[3] * k[3])));
        #pragma unroll
        for (int off = 32; off > 0; off >>= 1) d += __shfl_xor(d, off, 64);
        const float mn = fmaxf(m, d);
        const float cc = fexp2(m - mn);    // first iter: exp2(-inf)=0
        const float wt = fexp2(d - mn);
        l = fmaf(l, cc, wt);
        #pragma unroll
        for (int j = 0; j < 4; j++) a[j] = fmaf(a[j], cc, wt * x[j]);
        m = mn;
        if (i < 31) {
            #pragma unroll
            for (int j = 0; j < 4; j++) x[j] = xn[j];   // register rename, free
        }
    }

    #pragma unroll
    for (int j = 0; j < 4; j += 2)
        *(float2*)(&sacc[w][lane * 4 + j]) = make_float2(a[j], a[j+1]);
    if (lane == 0) { sM[w] = m; sL[w] = l; }
    __syncthreads();

    const float M  = fmaxf(fmaxf(sM[0], sM[1]), fmaxf(sM[2], sM[3]));
    const float c0 = fexp2(sM[0] - M), c1 = fexp2(sM[1] - M);
    const float c2 = fexp2(sM[2] - M), c3 = fexp2(sM[3] - M);
    const float acc = c0 * sacc[0][t] + c1 * sacc[1][t] + c2 * sacc[2][t] + c3 * sacc[3][t];
    float* o = part + ((size_t)b * NPART + p) * 260;
    o[t] = acc;
    if (t == 0) {
        o[256] = M;
        o[257] = c0 * sL[0] + c1 * sL[1] + c2 * sL[2] + c3 * sL[3];
    }
}

// ---------------------------------------------------------------------------
// comb: per-batch merge of 8 partials -> wf[b][f] (normalized attention-
// weighted feature sum).
__global__ __launch_bounds__(256) void comb_kernel(const float* __restrict__ part,
                                                   float* __restrict__ wf)
{
    const int b = blockIdx.x, t = threadIdx.x;
    const float* pb = part + (size_t)b * NPART * 260;
    float M = -INFINITY;
    #pragma unroll
    for (int p = 0; p < NPART; p++) M = fmaxf(M, pb[p * 260 + 256]);
    float L = 0.f, acc = 0.f;
    #pragma unroll
    for (int p = 0; p < NPART; p++) {
        const float cc = fexp2(pb[p * 260 + 256] - M);
        L   = fmaf(cc, pb[p * 260 + 257], L);
        acc = fmaf(cc, pb[p * 260 + t], acc);
    }
    wf[b * 256 + t] = (t < 255) ? acc / L : 0.f;
}

// ---------------------------------------------------------------------------
// res: resT[h][b] = vb[h] + sum_f wf[b][f]*vW[h][f]. 128 blocks, each an
// 8-row h-slice for all 128 batches; wf chunked through LDS [f][b].
__global__ __launch_bounds__(512) void res_kernel(const float* __restrict__ vW,
                                                  const float* __restrict__ vb,
                                                  const float* __restrict__ wf,
                                                  float* __restrict__ resT)
{
    __shared__ float vws[8][256];    // 8 KB
    __shared__ float wfs[64][130];   // 33.3 KB (pad 130: read banks (2f+b)&31 -> free)
    const int g = blockIdx.x, t = threadIdx.x;
    #pragma unroll
    for (int i = 0; i < 4; i++) {
        const int idx = i * 512 + t, f = idx & 255, hh = idx >> 8;
        vws[hh][f] = (f < 255) ? vW[(g * 8 + hh) * 255 + f] : 0.f;
    }
    const int b = t & 127, ho = t >> 7;      // ho wave-uniform (w>>1)
    const int fl = t & 63, wv = t >> 6;
    float acc0 = 0.f, acc1 = 0.f;
    for (int c = 0; c < 4; c++) {
        __syncthreads();
        #pragma unroll
        for (int i = 0; i < 16; i++) {
            const int bb = i * 8 + wv;
            wfs[fl][bb] = wf[bb * 256 + c * 64 + fl];   // coalesced global read
        }
        __syncthreads();
        #pragma unroll 8
        for (int f = 0; f < 64; f++) {
            const float w2 = wfs[f][b];
            acc0 = fmaf(w2, vws[ho][c * 64 + f], acc0);
            acc1 = fmaf(w2, vws[ho + 4][c * 64 + f], acc1);
        }
    }
    const int h0 = g * 8 + ho, h1 = h0 + 4;
    resT[h0 * 128 + b] = acc0 + vb[h0];
    resT[h1 * 128 + b] = acc1 + vb[h1];
}

// ---------------------------------------------------------------------------
// h1: h1pre[b][j] += sum_{h in kchunk} resT[h][b]*W1[j][h].
// Grid (32 jblk, 2 bhalf, 4 kchunk); K-split partials via f32 atomicAdd.
__global__ __launch_bounds__(256) void h1_kernel(const float* __restrict__ W1,
                                                 const float* __restrict__ resT,
                                                 float* __restrict__ h1pre)
{
    __shared__ float W1s[16][256];   // 16 KB
    __shared__ float ress[64][66];   // 16.9 KB
    const int j0 = blockIdx.x * 16, b0 = blockIdx.y * 64, h0 = blockIdx.z * 256;
    const int t = threadIdx.x;
    #pragma unroll
    for (int i = 0; i < 16; i++) {
        const int idx = i * 256 + t, hl = idx & 255, jj = idx >> 8;
        W1s[jj][hl] = W1[(j0 + jj) * 1024 + h0 + hl];
    }
    const int bb = t & 63, jg = t >> 6;      // jg wave-uniform
    float acc[4] = {0.f, 0.f, 0.f, 0.f};
    for (int sc = 0; sc < 4; sc++) {
        __syncthreads();
        {
            const int bl = t & 63, wvv = t >> 6;
            #pragma unroll
            for (int i = 0; i < 16; i++) {
                const int hl = i * 4 + wvv;
                ress[hl][bl] = resT[(h0 + sc * 64 + hl) * 128 + b0 + bl];
            }
        }
        __syncthreads();
        #pragma unroll 4
        for (int hl = 0; hl < 64; hl++) {
            const float rv = ress[hl][bb];
            acc[0] = fmaf(rv, W1s[jg * 4 + 0][sc * 64 + hl], acc[0]);
            acc[1] = fmaf(rv, W1s[jg * 4 + 1][sc * 64 + hl], acc[1]);
            acc[2] = fmaf(rv, W1s[jg * 4 + 2][sc * 64 + hl], acc[2]);
            acc[3] = fmaf(rv, W1s[jg * 4 + 3][sc * 64 + hl], acc[3]);
        }
    }
    #pragma unroll
    for (int k = 0; k < 4; k++)
        atomicAdd(&h1pre[(size_t)(b0 + bb) * 512 + j0 + jg * 4 + k], acc[k]);
}

// ---------------------------------------------------------------------------
// h2out: h2[b][j2] = relu(b2[j2] + sum_j W2[j2][j]*relu(h1pre[b][j]+b1[j]));
// then partial out[b][o] += sum_{j2 in block} h2 * W3[o][j2] via atomicAdd
// (d_out zero-initialized by qk_kernel). Grid (32 j2blk, 2 bhalf).
__global__ __launch_bounds__(256) void h2out_kernel(const float* __restrict__ W2,
    const float* __restrict__ b1, const float* __restrict__ b2,
    const float* __restrict__ W3, const float* __restrict__ b3,
    const float* __restrict__ h1pre, float* __restrict__ out)
{
    __shared__ float W2s[8][512];    // 16 KB
    __shared__ float h1s[64][66];    // 16.9 KB
    __shared__ float po[4][64][2];   // 2 KB
    const int j20 = blockIdx.x * 8, b0 = blockIdx.y * 64;
    const int t = threadIdx.x;
    #pragma unroll
    for (int i = 0; i < 16; i++) {
        const int idx = i * 256 + t, jl = idx & 511, jj = idx >> 9;
        W2s[jj][jl] = W2[(j20 + jj) * 512 + jl];
    }
    const int bb = t & 63, jg = t >> 6;
    float acc[2] = {0.f, 0.f};
    for (int sc = 0; sc < 8; sc++) {
        __syncthreads();
        {
            const int jl = t & 63, wvv = t >> 6;
            #pragma unroll
            for (int i = 0; i < 16; i++) {
                const int bl = i * 4 + wvv;
                const float v = h1pre[(size_t)(b0 + bl) * 512 + sc * 64 + jl] + b1[sc * 64 + jl];
                h1s[jl][bl] = fmaxf(v, 0.f);   // relu applied on load
            }
        }
        __syncthreads();
        #pragma unroll 4
        for (int jl = 0; jl < 64; jl++) {
            const float hv = h1s[jl][bb];
            acc[0] = fmaf(hv, W2s[jg * 2 + 0][sc * 64 + jl], acc[0]);
            acc[1] = fmaf(hv, W2s[jg * 2 + 1][sc * 64 + jl], acc[1]);
        }
    }
    float p0 = 0.f, p1 = 0.f;
    #pragma unroll
    for (int k = 0; k < 2; k++) {
        const int j2 = j20 + jg * 2 + k;
        const float h2v = fmaxf(acc[k] + b2[j2], 0.f);
        p0 = fmaf(h2v, W3[j2],       p0);
        p1 = fmaf(h2v, W3[256 + j2], p1);
    }
    po[jg][bb][0] = p0;
    po[jg][bb][1] = p1;
    __syncthreads();
    if (t < 128) {
        const int b = t & 63, o = t >> 6;
        float s = po[0][b][o] + po[1][b][o] + po[2][b][o] + po[3][b][o];
        if (blockIdx.x == 0) s += b3[o];     // add bias exactly once per (b,o)
        atomicAdd(&out[(b0 + b) * 2 + o], s);
    }
}

// ---------------------------------------------------------------------------
extern "C" void kernel_launch(void* const* d_in, const int* in_sizes, int n_in,
                              void* d_out, int out_size, void* d_ws, size_t ws_size,
                              hipStream_t stream)
{
    (void)in_sizes; (void)n_in; (void)out_size; (void)ws_size;
    const float* in = (const float*)d_in[0];
    const float* kW = (const float*)d_in[1];
    // d_in[2] = kb: unused — q.kb is a per-batch constant score shift (softmax-invariant)
    const float* vW = (const float*)d_in[3];
    const float* vb = (const float*)d_in[4];
    const float* qW = (const float*)d_in[5];
    const float* qb = (const float*)d_in[6];
    const float* W1 = (const float*)d_in[7];
    const float* b1 = (const float*)d_in[8];
    const float* W2 = (const float*)d_in[9];
    const float* b2 = (const float*)d_in[10];
    const float* W3 = (const float*)d_in[11];
    const float* b3 = (const float*)d_in[12];

    char* ws = (char*)d_ws;
    float* kqp   = (float*)(ws + WS_KQP);
    float* part  = (float*)(ws + WS_PART);
    float* wf    = (float*)(ws + WS_WF);
    float* resT  = (float*)(ws + WS_REST);
    float* h1pre = (float*)(ws + WS_H1P);

    qk_kernel   <<<dim3(64, 4),         256, 0, stream>>>(in, kW, qW, qb, kqp, h1pre, (float*)d_out);
    attn_kernel <<<dim3(NPART, NBATCH), 256, 0, stream>>>(in, kqp, part);
    comb_kernel <<<128,                 256, 0, stream>>>(part, wf);
    res_kernel  <<<128,                 512, 0, stream>>>(vW, vb, wf, resT);
    h1_kernel   <<<dim3(32, 2, 4),      256, 0, stream>>>(W1, resT, h1pre);
    h2out_kernel<<<dim3(32, 2),         256, 0, stream>>>(W2, b1, b2, W3, b3, h1pre, (float*)d_out);
}